// Round 1
// baseline (76.674 us; speedup 1.0000x reference)
//
#include <hip/hip_runtime.h>
#include <math.h>

#define NBBINS 50
#define NWAVES 4
#define QCAP   520   // per-wave queue capacity: ceil(2048/4)=512 jobs + 8 pad

#define TWO_PI_F 6.28318530717958647692f
#define FLAG_MAGIC 0x9E3779B97F4A7C15ULL   // cannot equal any constant poison fill

// -------- Fused kernel: per-disk_a density + last-block-done reduction -------
__global__ __launch_bounds__(256) void pcf_fused_kernel(
    const float* __restrict__ A, const float* __restrict__ B,
    const int* __restrict__ flagp, float* __restrict__ density,
    unsigned long long* __restrict__ flags, float* __restrict__ out,
    int na, int nb_in, float rmax, float inv_rmax, float gf)
{
    const int i    = blockIdx.x;
    const int tid  = threadIdx.x;
    const int wave = tid >> 6;
    const int lane = tid & 63;
    const int flag = flagp[0];                 // same_category (device-read)
    const float* __restrict__ Bp = flag ? A : B;
    const int nb = flag ? na : nb_in;          // loop count; division stays nb_in

    __shared__ float qnd[NWAVES * QCAP];
    __shared__ float part[NWAVES][NBBINS];
    __shared__ float sarc[8];

    const float ax  = A[3*i+0];
    const float ay  = A[3*i+1];
    const float arn = A[3*i+2] * inv_rmax;

    // ---- phase 1: each wave computes nd over its j-chunk, compacts nd<6.6
    const int nbw   = (nb + NWAVES - 1) / NWAVES;
    const int j0    = wave * nbw;
    const int j1    = min(j0 + nbw, nb);
    const int iters = (j1 - j0 + 63) >> 6;
    const int qbase = wave * QCAP;
    int nq = 0;

    for (int it = 0; it < iters; ++it) {
        const int j = j0 + it*64 + lane;
        const bool valid = (j < j1) && !(flag && j == i);
        float nd = 1e9f;
        if (valid) {
            const float bx  = Bp[3*j+0];
            const float by  = Bp[3*j+1];
            const float brn = Bp[3*j+2] * inv_rmax;
            const float dx = ax - bx, dy = ay - by;
            const float d  = sqrtf(dx*dx + dy*dy) * inv_rmax;
            const float r1 = fmaxf(arn, brn);
            const float r2 = fminf(arn, brn);
            const float extent  = fmaxf(d + r1 + r2, 2.0f*r1);
            const float overlap = fminf(fmaxf(r1 + r2 - d, 0.0f), 2.0f*r2);
            const float f = extent - overlap + d + r1 - r2;
            nd = f - 4.0f*r1 - 2.0f*r2 + 3.0f;           // disjoint (common)
            if (d <= r1 + r2) {                          // rare: contact/containment
                nd = (d <= r1 - r2)
                   ? f / (4.0f*r1 - 4.0f*r2 + 1e-8f)
                   : (f - 4.0f*r1 + 7.0f*r2) / (3.0f*r2 + 1e-8f);
            }
        }
        // beyond nd>=6.6 the nearest bin (5.0) sees exp(-16*1.6^2)~1.6e-18: negligible
        const bool pass = (nd < 6.6f);
        const unsigned long long m = __ballot(pass);
        if (pass) {
            const int pos = __popcll(m & ((1ull << lane) - 1ull));
            qnd[qbase + nq + pos] = nd;
        }
        nq += (int)__popcll(m);
    }
    if (lane < 8) qnd[qbase + nq + lane] = 1e9f;   // pad (exp2 -> 0, no NaN)

    // per-disk atan2 constants (8 total), computed once
    if (tid < 8) {
        const int b = tid >> 1;
        const float dxe = (b==0) ? ax : (b==1) ? (1.f-ax) : (b==2) ? ay : (1.f-ay);
        const float dyb = (b < 2) ? ay : ax;
        const float dye = (tid & 1) ? (1.f - dyb) : dyb;
        sarc[tid] = atan2f(dye, dxe);
    }

    // ---- phase 2: lane l accumulates bin l over this wave's queue
    const float rsn = 0.1f * (float)(lane + 1);    // rs/RMAX for bin 'lane'
    float acc = 0.f;
    const int rounds = (nq + 7) >> 3;
    for (int r = 0; r < rounds; ++r) {
        const float4 v0 = *(const float4*)&qnd[qbase + r*8];
        const float4 v1 = *(const float4*)&qnd[qbase + r*8 + 4];
        const float nds[8] = {v0.x, v0.y, v0.z, v0.w, v1.x, v1.y, v1.z, v1.w};
        #pragma unroll
        for (int u = 0; u < 8; ++u) {
            const float x = rsn - nds[u];
            acc += exp2f(-23.083120654223414f * (x * x));   // exp(-16 x^2)
        }
    }
    if (lane < NBBINS) part[wave][lane] = acc;
    __syncthreads();

    // ---- epilogue: perimeter weight + area, publish density[k][i] (device scope)
    if (tid < NBBINS) {
        const int k = tid;
        const float h = (part[0][k] + part[1][k] + part[2][k] + part[3][k]) * gf;

        const float rs = 0.1f*(float)(k+1) * rmax;
        float full = TWO_PI_F;
        #pragma unroll
        for (int b = 0; b < 4; ++b) {
            const float dxe = (b==0) ? ax : (b==1) ? (1.f-ax) : (b==2) ? ay : (1.f-ay);
            if (rs > dxe) {
                const float ratio = fminf(fmaxf(dxe / rs, -1.f), 1.f);
                const float alpha = acosf(ratio);
                full -= fminf(alpha, sarc[2*b]) + fminf(alpha, sarc[2*b+1]);
            }
        }
        float perim = full * (1.0f / TWO_PI_F);
        perim = fminf(fmaxf(perim, 0.f), 1.f);
        const float w = (perim > 1e-4f) ? (1.f / perim) : 0.f;

        const float inner = fmaxf(0.f, rs - 0.5f*rmax);
        const float outer = rs + 0.5f*rmax;
        const float area  = 3.14159265358979323846f * (outer*outer - inner*inner);

        const float dens = w * h / area / (float)nb_in;
        // sc1 write-through: visible at the device coherence point, no cross-XCD
        // L2 writeback/false-sharing hazard
        __hip_atomic_store(&density[k*na + i], dens,
                           __ATOMIC_RELAXED, __HIP_MEMORY_SCOPE_AGENT);
    }
    // release (same wave as the density stores -> orders after them via vmcnt)
    if (tid == 0)
        __hip_atomic_store(&flags[i], FLAG_MAGIC,
                           __ATOMIC_RELEASE, __HIP_MEMORY_SCOPE_AGENT);

    if (i != na - 1) return;   // only the last-dispatched block reduces

    // ---- last-block reduction (replaces old kernel 2) ----
    // Spin on flags with agent-scope loads (bypass local L2 -> no stale spin).
    // No deadlock: only this block spins; producers never wait on it.
    for (int f = tid; f < na; f += 256) {
        while (__hip_atomic_load(&flags[f], __ATOMIC_RELAXED,
                                 __HIP_MEMORY_SCOPE_AGENT) != FLAG_MAGIC) { }
    }
    __syncthreads();
    __threadfence();   // acquire: invalidate local L1/L2 before density reads

    for (int k = wave; k < NBBINS; k += NWAVES) {   // wave-parallel bins
        float s = 0.f, mn = 3.0e38f, mx = -3.0e38f;
        for (int ii = lane; ii < na; ii += 64) {    // 256 B coalesced per wave-load
            const float v = density[k*na + ii];
            s += v; mn = fminf(mn, v); mx = fmaxf(mx, v);
        }
        #pragma unroll
        for (int off = 32; off > 0; off >>= 1) {
            s  += __shfl_xor(s, off, 64);
            mn  = fminf(mn, __shfl_xor(mn, off, 64));
            mx  = fmaxf(mx, __shfl_xor(mx, off, 64));
        }
        if (lane == 0) {
            out[2*k]          = 0.1f*(float)(k+1);   // rs / RMAX
            out[2*k + 1]      = s / (float)na;       // pcf_mean
            out[2*NBBINS + k] = fminf(mn, 1e4f);     // pcf_lower
            out[3*NBBINS + k] = fmaxf(mx, 0.f);      // pcf_upper
        }
    }
}

extern "C" void kernel_launch(void* const* d_in, const int* in_sizes, int n_in,
                              void* d_out, int out_size, void* d_ws, size_t ws_size,
                              hipStream_t stream) {
    const float* A    = (const float*)d_in[0];
    const float* B    = (const float*)d_in[1];
    const int*   flag = (const int*)d_in[2];
    float* out = (float*)d_out;

    const int na = in_sizes[0] / 3;
    const int nb = in_sizes[1] / 3;

    const double rmax_d = 2.0 * sqrt(1.0 / (2.0 * sqrt(3.0) * 1024.0)); // NPOINTS=1024
    const float  rmax     = (float)rmax_d;
    const float  inv_rmax = (float)(1.0 / rmax_d);
    const float  gf       = (float)(1.0 / (sqrt(M_PI) * 0.25));         // SIGMA=0.25

    float* density = (float*)d_ws;  // NBBINS*na floats (transposed), 200 KB
    const size_t dens_bytes = ((size_t)NBBINS * (size_t)na * 4 + 7) & ~(size_t)7;
    unsigned long long* flags = (unsigned long long*)((char*)d_ws + dens_bytes);

    pcf_fused_kernel<<<na, 256, 0, stream>>>(A, B, flag, density, flags, out,
                                             na, nb, rmax, inv_rmax, gf);
}

// Round 2
// 26.536 us; speedup vs baseline: 2.8894x; 2.8894x over previous
//
#include <hip/hip_runtime.h>
#include <math.h>

#define NBBINS 50
#define NWAVES 4
#define QCAP   520   // per-wave queue capacity: ceil(2048/4)=512 jobs + 8 pad

#define TWO_PI_F 6.28318530717958647692f
#define FLAG_MAGIC 0x9E3779B97F4A7C15ULL   // cannot equal any constant poison fill

// -------- Fused kernel: per-disk_a density + 50 tail-block bin reducers ------
__global__ __launch_bounds__(256) void pcf_fused_kernel(
    const float* __restrict__ A, const float* __restrict__ B,
    const int* __restrict__ flagp, float* __restrict__ density,
    unsigned long long* __restrict__ flags, float* __restrict__ out,
    int na, int nb_in, float rmax, float inv_rmax, float gf)
{
    const int i    = blockIdx.x;
    const int tid  = threadIdx.x;
    const int wave = tid >> 6;
    const int lane = tid & 63;
    const int flag = flagp[0];                 // same_category (device-read)
    const float* __restrict__ Bp = flag ? A : B;
    const int nb = flag ? na : nb_in;          // loop count; division stays nb_in

    __shared__ float qnd[NWAVES * QCAP];
    __shared__ float part[NWAVES][NBBINS];
    __shared__ float sarc[8];
    __shared__ float ps[4], pmn[4], pmx[4];

    const float ax  = A[3*i+0];
    const float ay  = A[3*i+1];
    const float arn = A[3*i+2] * inv_rmax;

    // ---- phase 1: each wave computes nd over its j-chunk, compacts nd<6.6
    const int nbw   = (nb + NWAVES - 1) / NWAVES;
    const int j0    = wave * nbw;
    const int j1    = min(j0 + nbw, nb);
    const int iters = (j1 - j0 + 63) >> 6;
    const int qbase = wave * QCAP;
    int nq = 0;

    for (int it = 0; it < iters; ++it) {
        const int j = j0 + it*64 + lane;
        const bool valid = (j < j1) && !(flag && j == i);
        float nd = 1e9f;
        if (valid) {
            const float bx  = Bp[3*j+0];
            const float by  = Bp[3*j+1];
            const float brn = Bp[3*j+2] * inv_rmax;
            const float dx = ax - bx, dy = ay - by;
            const float d  = sqrtf(dx*dx + dy*dy) * inv_rmax;
            const float r1 = fmaxf(arn, brn);
            const float r2 = fminf(arn, brn);
            const float extent  = fmaxf(d + r1 + r2, 2.0f*r1);
            const float overlap = fminf(fmaxf(r1 + r2 - d, 0.0f), 2.0f*r2);
            const float f = extent - overlap + d + r1 - r2;
            nd = f - 4.0f*r1 - 2.0f*r2 + 3.0f;           // disjoint (common)
            if (d <= r1 + r2) {                          // rare: contact/containment
                nd = (d <= r1 - r2)
                   ? f / (4.0f*r1 - 4.0f*r2 + 1e-8f)
                   : (f - 4.0f*r1 + 7.0f*r2) / (3.0f*r2 + 1e-8f);
            }
        }
        // beyond nd>=6.6 the nearest bin (5.0) sees exp(-16*1.6^2)~1.6e-18: negligible
        const bool pass = (nd < 6.6f);
        const unsigned long long m = __ballot(pass);
        if (pass) {
            const int pos = __popcll(m & ((1ull << lane) - 1ull));
            qnd[qbase + nq + pos] = nd;
        }
        nq += (int)__popcll(m);
    }
    if (lane < 8) qnd[qbase + nq + lane] = 1e9f;   // pad (exp2 -> 0, no NaN)

    // per-disk atan2 constants (8 total), computed once
    if (tid < 8) {
        const int b = tid >> 1;
        const float dxe = (b==0) ? ax : (b==1) ? (1.f-ax) : (b==2) ? ay : (1.f-ay);
        const float dyb = (b < 2) ? ay : ax;
        const float dye = (tid & 1) ? (1.f - dyb) : dyb;
        sarc[tid] = atan2f(dye, dxe);
    }

    // ---- phase 2: lane l accumulates bin l over this wave's queue
    const float rsn = 0.1f * (float)(lane + 1);    // rs/RMAX for bin 'lane'
    float acc = 0.f;
    const int rounds = (nq + 7) >> 3;
    for (int r = 0; r < rounds; ++r) {
        const float4 v0 = *(const float4*)&qnd[qbase + r*8];
        const float4 v1 = *(const float4*)&qnd[qbase + r*8 + 4];
        const float nds[8] = {v0.x, v0.y, v0.z, v0.w, v1.x, v1.y, v1.z, v1.w};
        #pragma unroll
        for (int u = 0; u < 8; ++u) {
            const float x = rsn - nds[u];
            acc += exp2f(-23.083120654223414f * (x * x));   // exp(-16 x^2)
        }
    }
    if (lane < NBBINS) part[wave][lane] = acc;
    __syncthreads();

    // ---- epilogue: perimeter weight + area, publish density[k][i] (device scope)
    if (tid < NBBINS) {
        const int k = tid;
        const float h = (part[0][k] + part[1][k] + part[2][k] + part[3][k]) * gf;

        const float rs = 0.1f*(float)(k+1) * rmax;
        float full = TWO_PI_F;
        #pragma unroll
        for (int b = 0; b < 4; ++b) {
            const float dxe = (b==0) ? ax : (b==1) ? (1.f-ax) : (b==2) ? ay : (1.f-ay);
            if (rs > dxe) {
                const float ratio = fminf(fmaxf(dxe / rs, -1.f), 1.f);
                const float alpha = acosf(ratio);
                full -= fminf(alpha, sarc[2*b]) + fminf(alpha, sarc[2*b+1]);
            }
        }
        float perim = full * (1.0f / TWO_PI_F);
        perim = fminf(fmaxf(perim, 0.f), 1.f);
        const float w = (perim > 1e-4f) ? (1.f / perim) : 0.f;

        const float inner = fmaxf(0.f, rs - 0.5f*rmax);
        const float outer = rs + 0.5f*rmax;
        const float area  = 3.14159265358979323846f * (outer*outer - inner*inner);

        const float dens = w * h / area / (float)nb_in;
        // sc1 write-through: visible at the device coherence point, no cross-XCD
        // L2 writeback/false-sharing hazard
        __hip_atomic_store(&density[k*na + i], dens,
                           __ATOMIC_RELAXED, __HIP_MEMORY_SCOPE_AGENT);
    }
    // release (same wave as the density stores -> orders after them via vmcnt)
    if (tid == 0)
        __hip_atomic_store(&flags[i], FLAG_MAGIC,
                           __ATOMIC_RELEASE, __HIP_MEMORY_SCOPE_AGENT);

    // ---- tail: last NBBINS blocks each reduce one bin (restores kernel-2
    //      parallelism: 50 blocks x 256 threads, was 1 block in round 1) ----
    if (i < na - NBBINS) return;
    const int k = na - 1 - i;                  // bin owned by this block

    // wave 0 polls all flags (16/thread); waves 1-3 park at the barrier.
    // No deadlock: every block published its flag above before any spin.
    if (wave == 0) {
        for (int f = lane; f < na; f += 64) {
            while (__hip_atomic_load(&flags[f], __ATOMIC_RELAXED,
                                     __HIP_MEMORY_SCOPE_AGENT) != FLAG_MAGIC) { }
        }
    }
    __syncthreads();
    __threadfence();   // acquire: invalidate local caches before density reads

    // identical arithmetic order to the old standalone reduce kernel
    float s = 0.f, mn = 3.0e38f, mx = -3.0e38f;
    for (int ii = tid; ii < na; ii += 256) {
        const float v = density[k*na + ii];
        s += v; mn = fminf(mn, v); mx = fmaxf(mx, v);
    }
    #pragma unroll
    for (int off = 32; off > 0; off >>= 1) {
        s  += __shfl_xor(s, off, 64);
        mn  = fminf(mn, __shfl_xor(mn, off, 64));
        mx  = fmaxf(mx, __shfl_xor(mx, off, 64));
    }
    if (lane == 0) { ps[wave] = s; pmn[wave] = mn; pmx[wave] = mx; }
    __syncthreads();
    if (tid == 0) {
        float S = 0.f, MN = 3.0e38f, MX = -3.0e38f;
        #pragma unroll
        for (int wv = 0; wv < 4; ++wv) {
            S += ps[wv]; MN = fminf(MN, pmn[wv]); MX = fmaxf(MX, pmx[wv]);
        }
        out[2*k]          = 0.1f*(float)(k+1);   // rs / RMAX
        out[2*k + 1]      = S / (float)na;       // pcf_mean
        out[2*NBBINS + k] = fminf(MN, 1e4f);     // pcf_lower
        out[3*NBBINS + k] = fmaxf(MX, 0.f);      // pcf_upper
    }
}

extern "C" void kernel_launch(void* const* d_in, const int* in_sizes, int n_in,
                              void* d_out, int out_size, void* d_ws, size_t ws_size,
                              hipStream_t stream) {
    const float* A    = (const float*)d_in[0];
    const float* B    = (const float*)d_in[1];
    const int*   flag = (const int*)d_in[2];
    float* out = (float*)d_out;

    const int na = in_sizes[0] / 3;
    const int nb = in_sizes[1] / 3;

    const double rmax_d = 2.0 * sqrt(1.0 / (2.0 * sqrt(3.0) * 1024.0)); // NPOINTS=1024
    const float  rmax     = (float)rmax_d;
    const float  inv_rmax = (float)(1.0 / rmax_d);
    const float  gf       = (float)(1.0 / (sqrt(M_PI) * 0.25));         // SIGMA=0.25

    float* density = (float*)d_ws;  // NBBINS*na floats (transposed), 200 KB
    const size_t dens_bytes = ((size_t)NBBINS * (size_t)na * 4 + 7) & ~(size_t)7;
    unsigned long long* flags = (unsigned long long*)((char*)d_ws + dens_bytes);

    pcf_fused_kernel<<<na, 256, 0, stream>>>(A, B, flag, density, flags, out,
                                             na, nb, rmax, inv_rmax, gf);
}